// Round 1
// baseline (584.898 us; speedup 1.0000x reference)
//
#include <hip/hip_runtime.h>

// Problem constants (from reference):
//   B=4, N_POINTS=524288, NUM_PROPOSAL=256, FEAT_DIM=16, P=256, K_INST=32
//   M = P*4096 = 1,048,576 (proposals_idx rows)
// Output layout (flat float32, concatenated in return order):
//   batch          [B*NUM_PROPOSAL*FEAT_DIM] = 16384
//   proposal_mask  [B*NUM_PROPOSAL]          = 1024
//   scores_pred    [P]                       = 256
//   proposal_ious  [B*NUM_PROPOSAL*K_INST]   = 32768
//   proposals_pred [P*N_POINTS]              = 134217728
// Total = 134,268,160 floats (~537 MB) -> write-BW bound.

#define N_POINTS_C 524288
#define NUM_PROPOSAL_C 256
#define FEAT_DIM_C 16

// One block of 256 threads: per-proposal bookkeeping + tiny outputs.
__global__ void proposal_small_kernel(const float* __restrict__ scores,
                                      const float* __restrict__ feats,
                                      const float* __restrict__ ious,
                                      const int* __restrict__ pidx,
                                      const int* __restrict__ poff,
                                      const int* __restrict__ boff,
                                      int P, int nB, int K,
                                      float* __restrict__ out_batch,
                                      float* __restrict__ out_mask,
                                      float* __restrict__ out_spred,
                                      float* __restrict__ out_ious) {
    __shared__ int sb[NUM_PROPOSAL_C];
    const int p = threadIdx.x;
    int b = 0;
    if (p < P) {
        // first point id of proposal p
        const int fp = pidx[2 * poff[p] + 1];
        // b = searchsorted(batch_offsets, fp, 'right') - 1
        b = nB - 1;
        for (int j = 0; j < nB; ++j) {
            if (fp < boff[j + 1]) { b = j; break; }
        }
        sb[p] = b;
    }
    __syncthreads();
    if (p < P) {
        // slot = stable rank of p within its batch
        int slot = 0;
        for (int q = 0; q < p; ++q) slot += (sb[q] == b) ? 1 : 0;

        out_mask[b * NUM_PROPOSAL_C + slot] = 1.0f;
        out_spred[p] = 1.0f / (1.0f + expf(-scores[p]));

        const int dst_bs = b * NUM_PROPOSAL_C + slot;
        #pragma unroll
        for (int j = 0; j < FEAT_DIM_C; ++j)
            out_batch[dst_bs * FEAT_DIM_C + j] = feats[p * FEAT_DIM_C + j];
        for (int j = 0; j < K; ++j)
            out_ious[dst_bs * K + j] = ious[p * K + j];
    }
}

// Scatter 1.0f at (pid, ptid) into proposals_pred.
__global__ void scatter_ones_kernel(const int2* __restrict__ pidx,
                                    float* __restrict__ out_pp,
                                    int M) {
    const int i = blockIdx.x * blockDim.x + threadIdx.x;
    if (i < M) {
        const int2 e = pidx[i];  // e.x = pid, e.y = ptid
        out_pp[(size_t)e.x * N_POINTS_C + e.y] = 1.0f;
    }
}

extern "C" void kernel_launch(void* const* d_in, const int* in_sizes, int n_in,
                              void* d_out, int out_size, void* d_ws, size_t ws_size,
                              hipStream_t stream) {
    const float* scores = (const float*)d_in[0];   // (P,1)
    const float* feats  = (const float*)d_in[1];   // (P,16)
    const float* ious   = (const float*)d_in[2];   // (P,K)
    const int*   pidx   = (const int*)d_in[3];     // (M,2) int32
    const int*   poff   = (const int*)d_in[4];     // (P+1,)
    const int*   boff   = (const int*)d_in[5];     // (nB+1,)

    const int P  = in_sizes[0];
    const int K  = in_sizes[2] / P;
    const int M  = in_sizes[3] / 2;
    const int nB = in_sizes[5] - 1;

    float* out = (float*)d_out;
    float* out_batch = out;                                        // nB*256*16
    float* out_mask  = out_batch + (size_t)nB * NUM_PROPOSAL_C * FEAT_DIM_C;
    float* out_spred = out_mask  + (size_t)nB * NUM_PROPOSAL_C;
    float* out_ious  = out_spred + P;
    float* out_pp    = out_ious  + (size_t)nB * NUM_PROPOSAL_C * K;

    // Zero the whole output (harness poisons it with 0xAA before each call).
    hipMemsetAsync(d_out, 0, (size_t)out_size * sizeof(float), stream);

    // Tiny per-proposal outputs.
    proposal_small_kernel<<<1, 256, 0, stream>>>(scores, feats, ious, pidx,
                                                 poff, boff, P, nB, K,
                                                 out_batch, out_mask,
                                                 out_spred, out_ious);

    // Scatter the ones into proposals_pred.
    const int threads = 256;
    const int blocks  = (M + threads - 1) / threads;
    scatter_ones_kernel<<<blocks, threads, 0, stream>>>((const int2*)pidx,
                                                        out_pp, M);
}

// Round 2
// 551.283 us; speedup vs baseline: 1.0610x; 1.0610x over previous
//
#include <hip/hip_runtime.h>

// Problem constants (from reference):
//   B=4, N_POINTS=524288, NUM_PROPOSAL=256, FEAT_DIM=16, P=256, K_INST=32
//   M = P*4096 = 1,048,576 (proposals_idx rows)
// Output layout (flat float32, concatenated in return order):
//   batch          [B*NUM_PROPOSAL*FEAT_DIM] = 16384
//   proposal_mask  [B*NUM_PROPOSAL]          = 1024
//   scores_pred    [P]                       = 256
//   proposal_ious  [B*NUM_PROPOSAL*K_INST]   = 32768
//   proposals_pred [P*N_POINTS]              = 134217728
// Total = 134,268,160 floats (~537 MB) -> write-BW bound.
//
// Strategy: proposals_pred written EXACTLY ONCE via per-row-half LDS bitmap
// (no memset + scatter RMW double-touch). 512 blocks = 2 per row, 32 KB LDS
// bitmap each -> 2 blocks/CU, 32 waves/CU.

#define N_POINTS_C 524288
#define NUM_PROPOSAL_C 256
#define FEAT_DIM_C 16
#define SPLIT 2
#define HALF_WORDS (N_POINTS_C / 32 / SPLIT)   // 8192 words = 32 KB

// One block of 256 threads: zero small outputs + per-proposal bookkeeping.
__global__ void proposal_small_kernel(const float* __restrict__ scores,
                                      const float* __restrict__ feats,
                                      const float* __restrict__ ious,
                                      const int* __restrict__ pidx,
                                      const int* __restrict__ poff,
                                      const int* __restrict__ boff,
                                      int P, int nB, int K,
                                      float* __restrict__ out_batch,
                                      float* __restrict__ out_mask,
                                      float* __restrict__ out_spred,
                                      float* __restrict__ out_ious) {
    __shared__ int sb[NUM_PROPOSAL_C];
    const int p = threadIdx.x;

    // Zero batch / mask / ious regions (spred is written densely below).
    // batch starts at out_batch; mask and ious are contiguous after spred in
    // the flat layout, but we have separate pointers — zero each region.
    {
        const int nbatch = nB * NUM_PROPOSAL_C * FEAT_DIM_C;
        for (int i = p; i < nbatch; i += blockDim.x) out_batch[i] = 0.0f;
        const int nmask = nB * NUM_PROPOSAL_C;
        for (int i = p; i < nmask; i += blockDim.x) out_mask[i] = 0.0f;
        const int nious = nB * NUM_PROPOSAL_C * K;
        for (int i = p; i < nious; i += blockDim.x) out_ious[i] = 0.0f;
    }

    int b = 0;
    if (p < P) {
        const int fp = pidx[2 * poff[p] + 1];
        // b = searchsorted(batch_offsets, fp, 'right') - 1
        b = nB - 1;
        for (int j = 0; j < nB; ++j) {
            if (fp < boff[j + 1]) { b = j; break; }
        }
        sb[p] = b;
    }
    __syncthreads();
    if (p < P) {
        // slot = stable rank of p within its batch
        int slot = 0;
        for (int q = 0; q < p; ++q) slot += (sb[q] == b) ? 1 : 0;

        out_mask[b * NUM_PROPOSAL_C + slot] = 1.0f;
        out_spred[p] = 1.0f / (1.0f + expf(-scores[p]));

        const int dst_bs = b * NUM_PROPOSAL_C + slot;
        #pragma unroll
        for (int j = 0; j < FEAT_DIM_C; ++j)
            out_batch[dst_bs * FEAT_DIM_C + j] = feats[p * FEAT_DIM_C + j];
        for (int j = 0; j < K; ++j)
            out_ious[dst_bs * K + j] = ious[p * K + j];
    }
}

// Fused zero+scatter for proposals_pred: one block per (row, half).
// LDS bitmap for this half's columns, then single-pass float4 stream-out.
__global__ __launch_bounds__(1024, 2)
void proposals_pred_kernel(const int* __restrict__ pidx,
                           const int* __restrict__ poff,
                           float* __restrict__ out_pp) {
    __shared__ unsigned bm[HALF_WORDS];
    const int p    = blockIdx.x / SPLIT;
    const int part = blockIdx.x % SPLIT;
    const int tid  = threadIdx.x;
    const int lo   = part * (N_POINTS_C / SPLIT);
    const int hi   = lo + (N_POINTS_C / SPLIT);

    // 1) zero bitmap
    #pragma unroll
    for (int w = tid; w < HALF_WORDS; w += 1024) bm[w] = 0u;
    __syncthreads();

    // 2) set bits for this row's points landing in [lo, hi)
    const int s = poff[p];
    const int e = poff[p + 1];
    for (int i = s + tid; i < e; i += 1024) {
        const int pt = pidx[2 * i + 1];
        if (pt >= lo && pt < hi) {
            const int rel = pt - lo;
            atomicOr(&bm[rel >> 5], 1u << (rel & 31));
        }
    }
    __syncthreads();

    // 3) stream out as float4 (fully coalesced: lane i writes bytes 16*i..)
    float4* dst = (float4*)(out_pp + (size_t)p * N_POINTS_C + lo);
    const int nvec = (N_POINTS_C / SPLIT) / 4;  // 65536
    #pragma unroll 4
    for (int v = tid; v < nvec; v += 1024) {
        const unsigned w = bm[v >> 3];       // 8 lanes share a word (broadcast)
        const int sh = (v & 7) * 4;
        float4 o;
        o.x = ((w >> (sh + 0)) & 1u) ? 1.0f : 0.0f;
        o.y = ((w >> (sh + 1)) & 1u) ? 1.0f : 0.0f;
        o.z = ((w >> (sh + 2)) & 1u) ? 1.0f : 0.0f;
        o.w = ((w >> (sh + 3)) & 1u) ? 1.0f : 0.0f;
        dst[v] = o;
    }
}

extern "C" void kernel_launch(void* const* d_in, const int* in_sizes, int n_in,
                              void* d_out, int out_size, void* d_ws, size_t ws_size,
                              hipStream_t stream) {
    const float* scores = (const float*)d_in[0];   // (P,1)
    const float* feats  = (const float*)d_in[1];   // (P,16)
    const float* ious   = (const float*)d_in[2];   // (P,K)
    const int*   pidx   = (const int*)d_in[3];     // (M,2) int32
    const int*   poff   = (const int*)d_in[4];     // (P+1,)
    const int*   boff   = (const int*)d_in[5];     // (nB+1,)

    const int P  = in_sizes[0];
    const int K  = in_sizes[2] / P;
    const int nB = in_sizes[5] - 1;

    float* out = (float*)d_out;
    float* out_batch = out;                                        // nB*256*16
    float* out_mask  = out_batch + (size_t)nB * NUM_PROPOSAL_C * FEAT_DIM_C;
    float* out_spred = out_mask  + (size_t)nB * NUM_PROPOSAL_C;
    float* out_ious  = out_spred + P;
    float* out_pp    = out_ious  + (size_t)nB * NUM_PROPOSAL_C * K;

    // Tiny per-proposal outputs (also zeroes the small regions).
    proposal_small_kernel<<<1, 256, 0, stream>>>(scores, feats, ious, pidx,
                                                 poff, boff, P, nB, K,
                                                 out_batch, out_mask,
                                                 out_spred, out_ious);

    // Single-pass proposals_pred: zero+scatter fused via LDS bitmap.
    proposals_pred_kernel<<<P * SPLIT, 1024, 0, stream>>>(pidx, poff, out_pp);
}

// Round 4
// 531.560 us; speedup vs baseline: 1.1003x; 1.0371x over previous
//
#include <hip/hip_runtime.h>

// Problem constants (from reference):
//   B=4, N_POINTS=524288, NUM_PROPOSAL=256, FEAT_DIM=16, P=256, K_INST=32
//   M = P*4096 = 1,048,576 (proposals_idx rows)
// Output layout (flat float32, concatenated in return order):
//   batch          [B*NUM_PROPOSAL*FEAT_DIM] = 16384
//   proposal_mask  [B*NUM_PROPOSAL]          = 1024
//   scores_pred    [P]                       = 256
//   proposal_ious  [B*NUM_PROPOSAL*K_INST]   = 32768
//   proposals_pred [P*N_POINTS]              = 134217728
// Total = 134,268,160 floats (~537 MB) -> write-BW bound (floor ~86 us at
// the measured 6.24 TB/s fill rate). Harness poison fills (~440 us) dominate
// dur_us and are out of our control.
//
// Strategy: proposals_pred written EXACTLY ONCE via per-row-half LDS bitmap,
// streamed out with non-temporal float4 stores. Bookkeeping block fused into
// the same dispatch (block P*SPLIT).

#define N_POINTS_C 524288
#define NUM_PROPOSAL_C 256
#define FEAT_DIM_C 16
#define SPLIT 2
#define HALF_WORDS (N_POINTS_C / 32 / SPLIT)   // 8192 words = 32 KB

// Native vector type: __builtin_nontemporal_store requires a native vector,
// not HIP's float4 class.
typedef float vfloat4 __attribute__((ext_vector_type(4)));

__global__ __launch_bounds__(1024, 2)
void fused_kernel(const float* __restrict__ scores,
                  const float* __restrict__ feats,
                  const float* __restrict__ ious,
                  const int* __restrict__ pidx,
                  const int* __restrict__ poff,
                  const int* __restrict__ boff,
                  int P, int nB, int K,
                  float* __restrict__ out_batch,
                  float* __restrict__ out_mask,
                  float* __restrict__ out_spred,
                  float* __restrict__ out_ious,
                  float* __restrict__ out_pp) {
    __shared__ unsigned bm[HALF_WORDS];
    const int tid = threadIdx.x;

    if (blockIdx.x == (unsigned)(P * SPLIT)) {
        // ---- bookkeeping block: small outputs ----
        int* sb = (int*)bm;

        // Zero small regions (spred is written densely below).
        const int nbatch = nB * NUM_PROPOSAL_C * FEAT_DIM_C;
        for (int i = tid; i < nbatch; i += blockDim.x) out_batch[i] = 0.0f;
        const int nmask = nB * NUM_PROPOSAL_C;
        for (int i = tid; i < nmask; i += blockDim.x) out_mask[i] = 0.0f;
        const int nious = nB * NUM_PROPOSAL_C * K;
        for (int i = tid; i < nious; i += blockDim.x) out_ious[i] = 0.0f;

        const int p = tid;
        int b = 0;
        if (p < P) {
            const int fp = pidx[2 * poff[p] + 1];
            // b = searchsorted(batch_offsets, fp, 'right') - 1
            b = nB - 1;
            for (int j = 0; j < nB; ++j) {
                if (fp < boff[j + 1]) { b = j; break; }
            }
            sb[p] = b;
        }
        __syncthreads();
        if (p < P) {
            // slot = stable rank of p within its batch
            int slot = 0;
            for (int q = 0; q < p; ++q) slot += (sb[q] == b) ? 1 : 0;

            out_mask[b * NUM_PROPOSAL_C + slot] = 1.0f;
            out_spred[p] = 1.0f / (1.0f + expf(-scores[p]));

            const int dst_bs = b * NUM_PROPOSAL_C + slot;
            #pragma unroll
            for (int j = 0; j < FEAT_DIM_C; ++j)
                out_batch[dst_bs * FEAT_DIM_C + j] = feats[p * FEAT_DIM_C + j];
            for (int j = 0; j < K; ++j)
                out_ious[dst_bs * K + j] = ious[p * K + j];
        }
        return;
    }

    // ---- proposals_pred block: fused zero+scatter via LDS bitmap ----
    const int p    = blockIdx.x / SPLIT;
    const int part = blockIdx.x % SPLIT;
    const int lo   = part * (N_POINTS_C / SPLIT);
    const int hi   = lo + (N_POINTS_C / SPLIT);

    // 1) zero bitmap
    #pragma unroll
    for (int w = tid; w < HALF_WORDS; w += 1024) bm[w] = 0u;
    __syncthreads();

    // 2) set bits for this row's points landing in [lo, hi).
    //    Rows are 4096 long and offsets are multiples of 4096, so int4
    //    (two pairs per load) is always aligned & exact.
    {
        const int s = poff[p];
        const int e = poff[p + 1];
        const int4* pp4 = (const int4*)(pidx + 2 * s);
        const int npair2 = (e - s) / 2;
        for (int i = tid; i < npair2; i += 1024) {
            const int4 q = pp4[i];  // (pid0, pt0, pid1, pt1)
            if (q.y >= lo && q.y < hi) {
                const int rel = q.y - lo;
                atomicOr(&bm[rel >> 5], 1u << (rel & 31));
            }
            if (q.w >= lo && q.w < hi) {
                const int rel = q.w - lo;
                atomicOr(&bm[rel >> 5], 1u << (rel & 31));
            }
        }
        // odd remainder (not hit for this problem, kept for generality)
        if ((e - s) & 1) {
            if (tid == 0) {
                const int pt = pidx[2 * (e - 1) + 1];
                if (pt >= lo && pt < hi) {
                    const int rel = pt - lo;
                    atomicOr(&bm[rel >> 5], 1u << (rel & 31));
                }
            }
        }
    }
    __syncthreads();

    // 3) stream out as non-temporal float4 (fully coalesced).
    vfloat4* dst = (vfloat4*)(out_pp + (size_t)p * N_POINTS_C + lo);
    const int nvec = (N_POINTS_C / SPLIT) / 4;  // 65536
    #pragma unroll 4
    for (int v = tid; v < nvec; v += 1024) {
        const unsigned w = bm[v >> 3];       // 8 lanes share a word (broadcast)
        const int sh = (v & 7) * 4;
        vfloat4 o;
        o.x = ((w >> (sh + 0)) & 1u) ? 1.0f : 0.0f;
        o.y = ((w >> (sh + 1)) & 1u) ? 1.0f : 0.0f;
        o.z = ((w >> (sh + 2)) & 1u) ? 1.0f : 0.0f;
        o.w = ((w >> (sh + 3)) & 1u) ? 1.0f : 0.0f;
        __builtin_nontemporal_store(o, &dst[v]);
    }
}

extern "C" void kernel_launch(void* const* d_in, const int* in_sizes, int n_in,
                              void* d_out, int out_size, void* d_ws, size_t ws_size,
                              hipStream_t stream) {
    const float* scores = (const float*)d_in[0];   // (P,1)
    const float* feats  = (const float*)d_in[1];   // (P,16)
    const float* ious   = (const float*)d_in[2];   // (P,K)
    const int*   pidx   = (const int*)d_in[3];     // (M,2) int32
    const int*   poff   = (const int*)d_in[4];     // (P+1,)
    const int*   boff   = (const int*)d_in[5];     // (nB+1,)

    const int P  = in_sizes[0];
    const int K  = in_sizes[2] / P;
    const int nB = in_sizes[5] - 1;

    float* out = (float*)d_out;
    float* out_batch = out;                                        // nB*256*16
    float* out_mask  = out_batch + (size_t)nB * NUM_PROPOSAL_C * FEAT_DIM_C;
    float* out_spred = out_mask  + (size_t)nB * NUM_PROPOSAL_C;
    float* out_ious  = out_spred + P;
    float* out_pp    = out_ious  + (size_t)nB * NUM_PROPOSAL_C * K;

    // One dispatch: P*SPLIT bitmap blocks + 1 bookkeeping block.
    fused_kernel<<<P * SPLIT + 1, 1024, 0, stream>>>(scores, feats, ious, pidx,
                                                     poff, boff, P, nB, K,
                                                     out_batch, out_mask,
                                                     out_spred, out_ious,
                                                     out_pp);
}